// Round 4
// baseline (615.845 us; speedup 1.0000x reference)
//
#include <hip/hip_runtime.h>
#include <hip/hip_bf16.h>

// LSTM B=256 T=512 H=256 E=6 V=10 C=10. fp32 in/out.
// ROUND 19: pair-flag skewed pipeline (barrier-free steps, r16 retried with
// its two bugs fixed). r18 post-mortem: step = convoy sum (per-SIMD ~1300cy
// matrix + ~400cy LDS read-drain + ~350cy elem + ~150cy tail, phases serial
// because __syncthreads keeps all waves in-phase; m114 says cross-wave
// MFMA/VALU overlap is free if phases skew). r16 failed on (1) un-prefetched
// flag polls (~120cy LDS latency serial before each chunk x4) and (2)
// s_sleep wake quantization. This round:
//  - k-tile (64 rows) = wave-pair ownership; rotation order: own pair first
//    (chunk0 waits only on partner), then +1,+2,+3.
//  - flags PREFETCHED into regs at step end (right after own inc); per-chunk
//    check is a register compare; re-read only on miss (steady state: free).
//  - weights quantized into consumption order wa[rt][g][c] (static reg
//    indexing; runtime k-tile only in load addresses).
//  - i32 accumulation exactly associative -> rotated k-order bit-identical
//    (absmax must stay 0.0078125).
//  - one-time per-pair s_nop stagger injects skew; 2-buffer safety: a wave's
//    step-t write implies it passed all pairs' t-1 flags -> all t-2 reads
//    done. Spin: empty volatile-reload loop (no s_sleep).
// Structure otherwise r18: 128 blocks x 512 thr (8 waves, 2/SIMD), 2
// cols/block, INT8 MFMA 16x16x64, reg-resident per-row-quantized weights
// (wa[2][4][4]=128 VGPR), h @127 double-buffered LDS, bias folded into
// per-col x-table tblC (80 KB LDS), tb(t+1) prefetch, Z C-operand, per-gate
// elem chunks after that gate's final MFMA, single-rcp c-update, constant-
// index cndmask select.

typedef __attribute__((ext_vector_type(4))) int   int4v;
typedef __attribute__((ext_vector_type(4))) float float4v;

#define MFMA_I8(a, b, c) __builtin_amdgcn_mfma_i32_16x16x64_i8(a, b, c, 0, 0, 0)

#define K_TANH (-2.8853900817779268f)   // exp2(K_TANH*x) = e^(-2x)
#define K_SIG  (-1.4426950408889634f)   // exp2(K_SIG*x)  = e^(-x)

#define HSTRIDE 320                     // bytes per col in hbuf: 80 dw == 16 mod 32

__device__ __forceinline__ short f2b(float f) {
    __hip_bfloat16 b = __float2bfloat16(f); return *(short*)&b;
}
__device__ __forceinline__ float b2f(short s) {
    union { unsigned int u; float f; } v; v.u = ((unsigned int)(unsigned short)s) << 16; return v.f;
}
__device__ __forceinline__ float fexp2(float x) {
#if __has_builtin(__builtin_amdgcn_exp2f)
    return __builtin_amdgcn_exp2f(x);
#else
    return __expf(x * 0.6931471805599453f);
#endif
}
__device__ __forceinline__ float frcp(float x) { return __builtin_amdgcn_rcpf(x); }

__global__ __attribute__((amdgpu_flat_work_group_size(512, 512), amdgpu_waves_per_eu(2, 2)))
void lstm_i8(
    const int* __restrict__ x,
    const float* __restrict__ emb,
    const float* __restrict__ Wxg, const float* __restrict__ Whg, const float* __restrict__ bg,
    const float* __restrict__ Wxi, const float* __restrict__ Whi, const float* __restrict__ bi,
    const float* __restrict__ Wxf, const float* __restrict__ Whf, const float* __restrict__ bff,
    const float* __restrict__ Wxo, const float* __restrict__ Who, const float* __restrict__ bo,
    const float* __restrict__ Wp, const float* __restrict__ bp,
    float* __restrict__ out)
{
    const int tid = threadIdx.x, bid = blockIdx.x;
    const int c0 = bid * 2;                 // 2 batch columns per block
    const int w = tid >> 6, lane = tid & 63;
    const int pair = w >> 1;                // k-tile/pair id: rows 64*pair..64*pair+63
    const int l = lane & 15, q = lane >> 4;
    const int col = lane & 1;               // this thread's column (B n-parity)
    const int rtb = (lane >> 1) & 1;        // row-tile select bit
    const int si  = (lane >> 2) & 3;        // acc reg index
    const int rwb = 32 * w;                 // this wave's 32-row base
    const int row = rwb + 16 * rtb + 4 * q + si;   // this thread's hidden row

    __shared__ __align__(16) unsigned int hbuf[2][2 * HSTRIDE / 4];  // h i8 [parity][col][k]
    __shared__ __align__(16) short hfin[2 * 264];                    // final h bf16 [col][k]
    __shared__ unsigned char xdig2[512 * 2];                         // [t][col]
    __shared__ __align__(16) float tblC[2 * 10 * 1024];              // [col][d][row][4g], bias folded
    __shared__ float scaleL[4 * 256];                                // per-gate per-row max|W|
    __shared__ __align__(16) int wflag[4];                           // per-pair write counters

    const float* WxT[4] = {Wxg, Wxi, Wxf, Wxo};
    const float* WhT[4] = {Whg, Whi, Whf, Who};
    const float* bT[4]  = {bg, bi, bff, bo};

    // ---- init: zero h buf0, stage digits, zero flags ----
    if (tid < 2 * HSTRIDE / 4) hbuf[0][tid] = 0u;
    if (tid < 4) wflag[tid] = 0;
    for (int i = tid; i < 1024; i += 512)
        xdig2[i] = (unsigned char)x[(c0 + (i & 1)) * 512 + (i >> 1)];

    // ---- x-path table per col, bias + gate-scale folded: tblC[c][d][r][g] ----
    for (int i = tid; i < 5120; i += 512) {
        int cc  = i / 2560;                   // 0 or 1
        int rem = i - cc * 2560;              // [0,2560)
        int d = rem >> 8, r = rem & 255;
        float4v v;
        #pragma unroll
        for (int g = 0; g < 4; g++) {
            float s = 0.f;
            #pragma unroll
            for (int e = 0; e < 6; e++) s += WxT[g][r * 6 + e] * emb[d * 6 + e];
            v[g] = (s + bT[g][c0 + cc]) * (g == 0 ? K_TANH : K_SIG);
        }
        *(float4v*)&tblC[cc * 10240 + d * 1024 + r * 4] = v;
    }

    // ---- weight quantization: per-row scale, i8 A-frags in registers ----
    // wa[rt][g][c] holds k-tile (pair+c)&3 -> consumption-order, static reg idx.
    int4v wa[2][4][4];
    #pragma unroll
    for (int rt = 0; rt < 2; rt++) {
        #pragma unroll
        for (int g = 0; g < 4; g++) {
            const float* Wr = WhT[g] + (rwb + rt * 16 + l) * 256 + q * 16;
            float mx = 0.f;
            #pragma unroll
            for (int kt = 0; kt < 4; kt++)
                #pragma unroll
                for (int c4 = 0; c4 < 4; c4++) {
                    float4v v = *(const float4v*)(Wr + kt * 64 + c4 * 4);
                    #pragma unroll
                    for (int j = 0; j < 4; j++) mx = fmaxf(mx, fabsf(v[j]));
                }
            mx = fmaxf(mx, __shfl_xor(mx, 16));
            mx = fmaxf(mx, __shfl_xor(mx, 32));
            mx = fmaxf(mx, 1e-20f);
            if (q == 0) scaleL[g * 256 + rwb + rt * 16 + l] = mx;
            float qs = 127.f / mx;
            #pragma unroll
            for (int c = 0; c < 4; c++) {
                const int kt = (pair + c) & 3;     // runtime in ADDRESS only
                int4v f;
                #pragma unroll
                for (int dw = 0; dw < 4; dw++) {
                    float4v v = *(const float4v*)(Wr + kt * 64 + dw * 4);
                    int word = 0;
                    #pragma unroll
                    for (int byt = 0; byt < 4; byt++) {
                        int z = (int)rintf(v[byt] * qs);
                        word |= (z & 255) << (8 * byt);
                    }
                    f[dw] = word;
                }
                wa[rt][g][c] = f;
            }
        }
    }

    __syncthreads();   // scaleL/tblC/xdig2/hbuf[0]/wflag visible

    // ---- loop-invariant: dequant scales (this thread's row) ----
    float dscl[4];
    #pragma unroll
    for (int g = 0; g < 4; g++) {
        float kk = (g == 0 ? K_TANH : K_SIG) * (1.f / 16129.f);   // 127^2
        dscl[g] = scaleL[g * 256 + row] * kk;
    }

    const bool bi1 = (si & 1) != 0;
    const bool bi2 = (si & 2) != 0;
    const bool brt = rtb != 0;
    const float* tprow = tblC + col * 10240 + row * 4;
    const int hoff = col * HSTRIDE + row;

    // chunk c consumes k-tile (pair+c)&3
    const int kc0 = pair, kc1 = (pair + 1) & 3, kc2 = (pair + 2) & 3, kc3 = (pair + 3) & 3;
    volatile int* vf0 = (volatile int*)&wflag[kc0];
    volatile int* vf1 = (volatile int*)&wflag[kc1];
    volatile int* vf2 = (volatile int*)&wflag[kc2];
    volatile int* vf3 = (volatile int*)&wflag[kc3];
    const int ho0 = kc0 * 64, ho1 = kc1 * 64, ho2 = kc2 * 64, ho3 = kc3 * 64;

    const int4v Z = {0, 0, 0, 0};

    float cs = 0.f, hl = 0.f;

    // prefetch tb for t=0
    float4v tb;
    { int dg = xdig2[0 * 2 + col]; tb = *(const float4v*)(tprow + dg * 1024); }

    // skew injection: pair j starts ~j*550cy late (one-time, <1us total)
    for (int i = 0; i < pair * 50; i++) asm volatile("s_nop 7");

    int f0 = 0, f1 = 0, f2 = 0, f3 = 0;     // prefetched flag values

    for (int t = 0; t < 512; t++) {
        const int p = t & 1;
        const int tgt = t << 1;             // 2 incs/pair/step
        const char* hbase = (const char*)hbuf[p] + col * HSTRIDE + q * 16;

        // ---- chunk 0: own pair (waits only on partner) ----
        if (f0 < tgt) { do { f0 = *vf0; } while (f0 < tgt); }
        asm volatile("" ::: "memory");
        int4v hfA = *(const int4v*)(hbase + ho0);
        int4v ag0 = MFMA_I8(wa[0][0][0], hfA, Z);
        int4v ag1 = MFMA_I8(wa[1][0][0], hfA, Z);
        int4v ai0 = MFMA_I8(wa[0][1][0], hfA, Z);
        int4v ai1 = MFMA_I8(wa[1][1][0], hfA, Z);
        int4v af0 = MFMA_I8(wa[0][2][0], hfA, Z);
        int4v af1 = MFMA_I8(wa[1][2][0], hfA, Z);
        int4v ao0 = MFMA_I8(wa[0][3][0], hfA, Z);
        int4v ao1 = MFMA_I8(wa[1][3][0], hfA, Z);

        // ---- chunk 1 ----
        if (f1 < tgt) { do { f1 = *vf1; } while (f1 < tgt); }
        asm volatile("" ::: "memory");
        int4v hfB = *(const int4v*)(hbase + ho1);
        ag0 = MFMA_I8(wa[0][0][1], hfB, ag0);
        ag1 = MFMA_I8(wa[1][0][1], hfB, ag1);
        ai0 = MFMA_I8(wa[0][1][1], hfB, ai0);
        ai1 = MFMA_I8(wa[1][1][1], hfB, ai1);
        af0 = MFMA_I8(wa[0][2][1], hfB, af0);
        af1 = MFMA_I8(wa[1][2][1], hfB, af1);
        ao0 = MFMA_I8(wa[0][3][1], hfB, ao0);
        ao1 = MFMA_I8(wa[1][3][1], hfB, ao1);

        // ---- chunk 2 ----
        if (f2 < tgt) { do { f2 = *vf2; } while (f2 < tgt); }
        asm volatile("" ::: "memory");
        int4v hfC = *(const int4v*)(hbase + ho2);
        ag0 = MFMA_I8(wa[0][0][2], hfC, ag0);
        ag1 = MFMA_I8(wa[1][0][2], hfC, ag1);
        ai0 = MFMA_I8(wa[0][1][2], hfC, ai0);
        ai1 = MFMA_I8(wa[1][1][2], hfC, ai1);
        af0 = MFMA_I8(wa[0][2][2], hfC, af0);
        af1 = MFMA_I8(wa[1][2][2], hfC, af1);
        ao0 = MFMA_I8(wa[0][3][2], hfC, ao0);
        ao1 = MFMA_I8(wa[1][3][2], hfC, ao1);

        // prefetch tb for t+1 (tblC, independent of h)
        float4v tbn;
        { int dgn = xdig2[((t + 1) & 511) * 2 + col]; tbn = *(const float4v*)(tprow + dgn * 1024); }

        // ---- chunk 3: per-gate final MFMA + that gate's elem chunk ----
        if (f3 < tgt) { do { f3 = *vf3; } while (f3 < tgt); }
        asm volatile("" ::: "memory");
        int4v hfD = *(const int4v*)(hbase + ho3);

        ag0 = MFMA_I8(wa[0][0][3], hfD, ag0);
        ag1 = MFMA_I8(wa[1][0][3], hfD, ag1);
        int avg_;
        { int t0 = bi1 ? ag0[1] : ag0[0]; int t1 = bi1 ? ag0[3] : ag0[2]; int s0 = bi2 ? t1 : t0;
          int u0 = bi1 ? ag1[1] : ag1[0]; int u1 = bi1 ? ag1[3] : ag1[2]; int s1 = bi2 ? u1 : u0;
          avg_ = brt ? s1 : s0; }
        float pg = fmaf((float)avg_, dscl[0], tb[0]);
        float Eg = fexp2(pg);

        ai0 = MFMA_I8(wa[0][1][3], hfD, ai0);
        ai1 = MFMA_I8(wa[1][1][3], hfD, ai1);
        int avi_;
        { int t0 = bi1 ? ai0[1] : ai0[0]; int t1 = bi1 ? ai0[3] : ai0[2]; int s0 = bi2 ? t1 : t0;
          int u0 = bi1 ? ai1[1] : ai1[0]; int u1 = bi1 ? ai1[3] : ai1[2]; int s1 = bi2 ? u1 : u0;
          avi_ = brt ? s1 : s0; }
        float pi = fmaf((float)avi_, dscl[1], tb[1]);
        float Ei = fexp2(pi);
        float m1 = (1.f + Eg) * (1.f + Ei);

        af0 = MFMA_I8(wa[0][2][3], hfD, af0);
        af1 = MFMA_I8(wa[1][2][3], hfD, af1);
        int avf_;
        { int t0 = bi1 ? af0[1] : af0[0]; int t1 = bi1 ? af0[3] : af0[2]; int s0 = bi2 ? t1 : t0;
          int u0 = bi1 ? af1[1] : af1[0]; int u1 = bi1 ? af1[3] : af1[2]; int s1 = bi2 ? u1 : u0;
          avf_ = brt ? s1 : s0; }
        float pf = fmaf((float)avf_, dscl[2], tb[2]);
        float Ef = fexp2(pf);
        float fp1 = 1.f + Ef;
        float num = fmaf(cs, m1, (1.f - Eg) * fp1);
        float c   = num * frcp(m1 * fp1);
        cs = c;
        float Ec = fexp2(K_TANH * c);

        ao0 = MFMA_I8(wa[0][3][3], hfD, ao0);
        ao1 = MFMA_I8(wa[1][3][3], hfD, ao1);
        int avo_;
        { int t0 = bi1 ? ao0[1] : ao0[0]; int t1 = bi1 ? ao0[3] : ao0[2]; int s0 = bi2 ? t1 : t0;
          int u0 = bi1 ? ao1[1] : ao1[0]; int u1 = bi1 ? ao1[3] : ao1[2]; int s1 = bi2 ? u1 : u0;
          avo_ = brt ? s1 : s0; }
        float po = fmaf((float)avo_, dscl[3], tb[3]);
        float Eo = fexp2(po);
        float hh = (1.f - Ec) * frcp((1.f + Ec) * (1.f + Eo));   // tanh(c)*sig(o)
        hl = hh;

        // own h byte -> other buffer (this wave's 64 (row,col) elems = its pair-half)
        *((char*)hbuf[1 - p] + hoff) = (char)((int)rintf(hh * 127.f));

        // publish: drain own DS writes, then release-inc own pair flag
        asm volatile("s_waitcnt lgkmcnt(0)" ::: "memory");
        if (lane == 0)
            __hip_atomic_fetch_add(&wflag[pair], 1, __ATOMIC_RELAXED, __HIP_MEMORY_SCOPE_WORKGROUP);

        // prefetch flags for next step (monotonic: stale-low re-read on miss)
        f0 = *vf0; f1 = *vf1; f2 = *vf2; f3 = *vf3;

        tb = tbn;
    }

    __syncthreads();   // all waves finished step 511

    // ---- stage final h (exact f32->bf16) for projection ----
    hfin[col * 264 + row] = f2b(hl);
    __syncthreads();

    // ---- projection: out[c0+col][cls] = Wp[cls] . h_final + bp[cls] ----
    if (tid < 20) {
        int pc = tid / 10, cls = tid - pc * 10;
        const short* hcol = &hfin[pc * 264];
        const float* wrow = Wp + cls * 256;
        float s = 0.f;
        #pragma unroll 8
        for (int k = 0; k < 256; k++) s += b2f(hcol[k]) * wrow[k];
        out[(c0 + pc) * 10 + cls] = s + bp[cls];
    }
}

extern "C" void kernel_launch(void* const* d_in, const int* in_sizes, int n_in,
                              void* d_out, int out_size, void* d_ws, size_t ws_size,
                              hipStream_t stream) {
    const int*   x   = (const int*)d_in[0];
    const float* emb = (const float*)d_in[1];
    const float* Wxg = (const float*)d_in[2];
    const float* Whg = (const float*)d_in[3];
    const float* bg  = (const float*)d_in[4];
    const float* Wxi = (const float*)d_in[5];
    const float* Whi = (const float*)d_in[6];
    const float* bi  = (const float*)d_in[7];
    const float* Wxf = (const float*)d_in[8];
    const float* Whf = (const float*)d_in[9];
    const float* bff = (const float*)d_in[10];
    const float* Wxo = (const float*)d_in[11];
    const float* Who = (const float*)d_in[12];
    const float* bo  = (const float*)d_in[13];
    const float* Wp  = (const float*)d_in[14];
    const float* bp  = (const float*)d_in[15];

    hipLaunchKernelGGL(lstm_i8, dim3(128), dim3(512), 0, stream,
                       x, emb, Wxg, Whg, bg, Wxi, Whi, bi, Wxf, Whf, bff,
                       Wxo, Who, bo, Wp, bp, (float*)d_out);
}